// Round 1
// baseline (825.877 us; speedup 1.0000x reference)
//
#include <hip/hip_runtime.h>
#include <cstdint>
#include <cmath>

typedef _Float16 f16;
using f16x8 = __attribute__((ext_vector_type(8))) _Float16;
using f16x4 = __attribute__((ext_vector_type(4))) _Float16;
using f32x4 = __attribute__((ext_vector_type(4))) float;

#define NHEAD 16
#define SEQ   2048
#define HDIM  2048
#define NEG_INF -3.0e38f

static __device__ __forceinline__ f32x4 mfma16(f16x8 a, f16x8 b, f32x4 c) {
    return __builtin_amdgcn_mfma_f32_16x16x32_f16(a, b, c, 0, 0, 0);
}

// ---------------- convert f32 -> f16 (with zero-padding tail) ----------------
__global__ __launch_bounds__(256) void k_cvt(const float* __restrict__ src, f16* __restrict__ dst,
                                             int n_valid, int n_total)
{
    int i = (blockIdx.x * 256 + threadIdx.x) * 4;
    if (i >= n_total) return;
    f16x4 o;
#pragma unroll
    for (int k = 0; k < 4; k++) {
        int idx = i + k;
        float v = (idx < n_valid) ? src[idx] : 0.f;
        o[k] = (f16)v;
    }
    *(f16x4*)&dst[i] = o;
}

// ---------------- RoPE cos/sin table: cs[t*64 + j] = cos, cs[t*64+32+j] = sin ----------------
__global__ void k_rope_table(float* __restrict__ cs)
{
    int t = blockIdx.x;
    int j = threadIdx.x;            // 0..31
    float invf = (float)pow(10000.0, -(double)j / 32.0);
    float ang  = (float)t * invf;   // f32 product, matches reference
    cs[t * 64 + j]      = (float)cos((double)ang);
    cs[t * 64 + 32 + j] = (float)sin((double)ang);
}

// ---------------- generic fp16 GEMM: C[M][ldc] = A[M][K] * B[N][K]^T (f32 out) ----------------
// tiles: 128x128, BK=32, 256 threads = 4 waves each 64x64
__global__ __launch_bounds__(256) void k_gemm(const f16* __restrict__ A, const f16* __restrict__ B,
                                              float* __restrict__ C, int K, int ldc)
{
    __shared__ __align__(16) f16 As[128 * 32];
    __shared__ __align__(16) f16 Bs[128 * 32];
    const int tid  = threadIdx.x;
    const int lane = tid & 63;
    const int wv   = tid >> 6;
    const int l15  = lane & 15;
    const int lg   = lane >> 4;
    const int m0   = blockIdx.y * 128;
    const int n0   = blockIdx.x * 128;
    const int wm   = (wv >> 1) * 64;
    const int wn   = (wv & 1) * 64;

    f32x4 acc[4][4] = {};

    const int r0  = tid >> 2;          // 0..63
    const int kc0 = (tid & 3) * 8;     // 0,8,16,24

    for (int kt = 0; kt < K; kt += 32) {
        f16x8 a0 = *(const f16x8*)&A[(size_t)(m0 + r0) * K + kt + kc0];
        f16x8 a1 = *(const f16x8*)&A[(size_t)(m0 + r0 + 64) * K + kt + kc0];
        f16x8 b0 = *(const f16x8*)&B[(size_t)(n0 + r0) * K + kt + kc0];
        f16x8 b1 = *(const f16x8*)&B[(size_t)(n0 + r0 + 64) * K + kt + kc0];
        __syncthreads();                      // prev compute done before overwrite
        *(f16x8*)&As[(size_t)tid * 8]         = a0;
        *(f16x8*)&As[(size_t)(tid + 256) * 8] = a1;
        *(f16x8*)&Bs[(size_t)tid * 8]         = b0;
        *(f16x8*)&Bs[(size_t)(tid + 256) * 8] = b1;
        __syncthreads();
        f16x8 af[4], bf[4];
#pragma unroll
        for (int i = 0; i < 4; i++)
            af[i] = *(const f16x8*)&As[(wm + i * 16 + l15) * 32 + lg * 8];
#pragma unroll
        for (int i = 0; i < 4; i++)
            bf[i] = *(const f16x8*)&Bs[(wn + i * 16 + l15) * 32 + lg * 8];
#pragma unroll
        for (int i = 0; i < 4; i++)
#pragma unroll
            for (int j = 0; j < 4; j++)
                acc[i][j] = mfma16(af[i], bf[j], acc[i][j]);
    }
#pragma unroll
    for (int i = 0; i < 4; i++) {
#pragma unroll
        for (int j = 0; j < 4; j++) {
            const int row = m0 + wm + i * 16 + lg * 4;
            const int col = n0 + wn + j * 16 + l15;
#pragma unroll
            for (int r = 0; r < 4; r++)
                C[(size_t)(row + r) * ldc + col] = acc[i][j][r];
        }
    }
}

// ---------------- RMS norm (q path): [2048][1536] f32 -> f16 ----------------
__global__ __launch_bounds__(256) void k_rms_q(const float* __restrict__ X, const float* __restrict__ w,
                                               f16* __restrict__ Y)
{
    const int row = blockIdx.x, tid = threadIdx.x;
    const float* x = &X[(size_t)row * 1536];
    float ss = 0.f;
    for (int c = tid; c < 1536; c += 256) { float v = x[c]; ss += v * v; }
#pragma unroll
    for (int off = 32; off > 0; off >>= 1) ss += __shfl_xor(ss, off);
    __shared__ float part[4];
    if ((tid & 63) == 0) part[tid >> 6] = ss;
    __syncthreads();
    float tot = part[0] + part[1] + part[2] + part[3];
    float sc = 1.f / sqrtf(tot / 1536.f + 1e-6f);
    for (int c = tid; c < 1536; c += 256)
        Y[(size_t)row * 1536 + c] = (f16)(w[c] * x[c] * sc);
}

// ---------------- RMS norm (kv path) + RoPE on k_pe ----------------
// X: [2048][640] (576 valid), -> latent16 [2048][512], Krope [2048][64]
__global__ __launch_bounds__(256) void k_rms_kv(const float* __restrict__ X, const float* __restrict__ w,
                                                f16* __restrict__ Lat, f16* __restrict__ Krope,
                                                const float* __restrict__ cs)
{
    const int row = blockIdx.x, tid = threadIdx.x;
    const float* x = &X[(size_t)row * 640];
    float ss = 0.f;
    for (int c = tid; c < 576; c += 256) { float v = x[c]; ss += v * v; }
#pragma unroll
    for (int off = 32; off > 0; off >>= 1) ss += __shfl_xor(ss, off);
    __shared__ float part[4];
    if ((tid & 63) == 0) part[tid >> 6] = ss;
    __syncthreads();
    float tot = part[0] + part[1] + part[2] + part[3];
    float sc = 1.f / sqrtf(tot / 576.f + 1e-6f);
    for (int c = tid; c < 512; c += 256)
        Lat[(size_t)row * 512 + c] = (f16)(w[c] * x[c] * sc);
    if (tid < 32) {
        int j = tid;
        float a = w[512 + 2 * j] * x[512 + 2 * j] * sc;
        float b = w[512 + 2 * j + 1] * x[512 + 2 * j + 1] * sc;
        float cv = cs[row * 64 + j], sv = cs[row * 64 + 32 + j];
        Krope[row * 64 + j]      = (f16)(a * cv - b * sv);
        Krope[row * 64 + 32 + j] = (f16)(b * cv + a * sv);
    }
}

// ---------------- assemble Q: q_all [2048][3072] f32 -> Qf [16][2048][192] f16 (rope'd) ----------------
__global__ __launch_bounds__(256) void k_asm_q(const float* __restrict__ q_all, const float* __restrict__ cs,
                                               f16* __restrict__ Qf)
{
    size_t idx = (size_t)blockIdx.x * 256 + threadIdx.x;
    if (idx >= (size_t)16 * 2048 * 192) return;
    int d = (int)(idx % 192);
    size_t hs = idx / 192;
    int s = (int)(hs % 2048);
    int h = (int)(hs / 2048);
    const float* qrow = &q_all[(size_t)s * 3072 + h * 192];
    float v;
    if (d < 64) {
        int j = d & 31;
        float a = qrow[128 + 2 * j], b = qrow[128 + 2 * j + 1];
        float cv = cs[s * 64 + j], sv = cs[s * 64 + 32 + j];
        v = (d < 32) ? (a * cv - b * sv) : (b * cv + a * sv);
    } else {
        v = qrow[d - 64];
    }
    Qf[idx] = (f16)v;
}

// ---------------- assemble K_nope + V^T from kv_all [2048][4096] f32 ----------------
__global__ __launch_bounds__(256) void k_asm_kv(const float* __restrict__ kv_all,
                                                f16* __restrict__ Knope,  // [16][2048][128]
                                                f16* __restrict__ Vt)     // [16][128][2048]
{
    size_t idx = (size_t)blockIdx.x * 256 + threadIdx.x;
    if (idx >= (size_t)16 * 2048 * 256) return;
    int d = (int)(idx % 256);
    size_t hs = idx / 256;
    int s = (int)(hs % 2048);
    int h = (int)(hs / 2048);
    float v = kv_all[(size_t)s * 4096 + h * 256 + d];
    if (d < 128)
        Knope[((size_t)h * 2048 + s) * 128 + d] = (f16)v;
    else
        Vt[((size_t)h * 128 + (d - 128)) * 2048 + s] = (f16)v;
}

// ---------------- fused causal attention ----------------
// grid (32 qtiles, 16 heads), 256 thr = 4 waves; wave owns 16 q-rows; barrier-free.
__global__ __launch_bounds__(256) void k_attn(
    const f16* __restrict__ Qf,     // [16][2048][192] (rope|nope)
    const f16* __restrict__ Krope,  // [2048][64]
    const f16* __restrict__ Knope,  // [16][2048][128]
    const f16* __restrict__ Vt,     // [16][128][2048]
    float* __restrict__ attnw,      // [16][2048][2048]
    f16* __restrict__ Ohead)        // [2048][16*128]  (s, h*128+d)
{
    const int h  = blockIdx.y;
    const int q0 = blockIdx.x * 64;
    const int tid = threadIdx.x;
    const int lane = tid & 63;
    const int wv = tid >> 6;
    const int l15 = lane & 15;
    const int lg  = lane >> 4;
    const int rowb = q0 + wv * 16;

    __shared__ __align__(16) f16 Plds[4][16][72];

    f16x8 qf[6];
    {
        const f16* qbase = &Qf[((size_t)h * SEQ + rowb + l15) * 192];
#pragma unroll
        for (int kf = 0; kf < 6; kf++)
            qf[kf] = *(const f16x8*)&qbase[kf * 32 + lg * 8];
    }

    float m[4], l[4];
#pragma unroll
    for (int r = 0; r < 4; r++) { m[r] = NEG_INF; l[r] = 0.f; }

    const int ntiles = q0 / 64 + 1;
    const f32x4 vzero = {0.f, 0.f, 0.f, 0.f};

    auto computeS = [&](int c0, f32x4 (&s)[4]) {
#pragma unroll
        for (int ni = 0; ni < 4; ni++) {
            s[ni] = vzero;
            const int colr = c0 + ni * 16 + l15;
            const f16* krp = &Krope[(size_t)colr * 64 + lg * 8];
            const f16* knp = &Knope[((size_t)h * SEQ + colr) * 128 + lg * 8];
            s[ni] = mfma16(qf[0], *(const f16x8*)&krp[0],  s[ni]);
            s[ni] = mfma16(qf[1], *(const f16x8*)&krp[32], s[ni]);
#pragma unroll
            for (int kf = 0; kf < 4; kf++)
                s[ni] = mfma16(qf[2 + kf], *(const f16x8*)&knp[kf * 32], s[ni]);
        }
    };

    // ---- pass 1: row max / row sum ----
    for (int t = 0; t < ntiles; t++) {
        const int c0 = t * 64;
        f32x4 s[4];
        computeS(c0, s);
        float vmax[4] = {NEG_INF, NEG_INF, NEG_INF, NEG_INF};
#pragma unroll
        for (int ni = 0; ni < 4; ni++) {
            const int col = c0 + ni * 16 + l15;
#pragma unroll
            for (int r = 0; r < 4; r++) {
                const int row = rowb + lg * 4 + r;
                float v = (col <= row) ? s[ni][r] : NEG_INF;
                s[ni][r] = v;
                vmax[r] = fmaxf(vmax[r], v);
            }
        }
#pragma unroll
        for (int off = 1; off < 16; off <<= 1)
#pragma unroll
            for (int r = 0; r < 4; r++)
                vmax[r] = fmaxf(vmax[r], __shfl_xor(vmax[r], off));
#pragma unroll
        for (int r = 0; r < 4; r++) {
            const float nm = fmaxf(m[r], vmax[r]);
            float es = 0.f;
#pragma unroll
            for (int ni = 0; ni < 4; ni++) es += expf(s[ni][r] - nm);
#pragma unroll
            for (int off = 1; off < 16; off <<= 1) es += __shfl_xor(es, off);
            l[r] = l[r] * expf(m[r] - nm) + es;
            m[r] = nm;
        }
    }

    float rl[4];
#pragma unroll
    for (int r = 0; r < 4; r++) rl[r] = 1.f / l[r];

    // ---- pass 2: P write + P*V ----
    f32x4 o[8] = {};
    for (int t = 0; t < ntiles; t++) {
        const int c0 = t * 64;
        f32x4 s[4];
        computeS(c0, s);
#pragma unroll
        for (int ni = 0; ni < 4; ni++) {
            const int col = c0 + ni * 16 + l15;
#pragma unroll
            for (int r = 0; r < 4; r++) {
                const int row = rowb + lg * 4 + r;
                float p = (col <= row) ? expf(s[ni][r] - m[r]) * rl[r] : 0.f;
                attnw[((size_t)h * SEQ + row) * SEQ + col] = p;
                Plds[wv][lg * 4 + r][ni * 16 + l15] = (f16)p;
            }
        }
        asm volatile("" ::: "memory");  // keep LDS writes before reads
        f16x8 pa0 = *(const f16x8*)&Plds[wv][l15][lg * 8];
        f16x8 pa1 = *(const f16x8*)&Plds[wv][l15][32 + lg * 8];
#pragma unroll
        for (int nd = 0; nd < 8; nd++) {
            const f16* vtp = &Vt[((size_t)h * 128 + nd * 16 + l15) * SEQ + c0 + lg * 8];
            o[nd] = mfma16(pa0, *(const f16x8*)&vtp[0],  o[nd]);
            o[nd] = mfma16(pa1, *(const f16x8*)&vtp[32], o[nd]);
        }
    }

    // ---- O write ----
#pragma unroll
    for (int nd = 0; nd < 8; nd++)
#pragma unroll
        for (int r = 0; r < 4; r++) {
            const int row = rowb + lg * 4 + r;
            Ohead[(size_t)row * 2048 + h * 128 + nd * 16 + l15] = (f16)o[nd][r];
        }

    // ---- zero-fill cols >= q0+64 for this block's 64 rows ----
    const int cstart = q0 + 64;
    const int zc = SEQ - cstart;
    if (zc > 0) {
        const int nchunk = zc >> 2;
        for (int i = tid; i < 64 * nchunk; i += 256) {
            const int r  = i / nchunk;
            const int cc = (i - r * nchunk) << 2;
            *(f32x4*)&attnw[((size_t)h * SEQ + q0 + r) * SEQ + cstart + cc] = vzero;
        }
    }
}

// ---------------- final GEMM writes f32 directly to d_out tail ----------------

extern "C" void kernel_launch(void* const* d_in, const int* in_sizes, int n_in,
                              void* d_out, int out_size, void* d_ws, size_t ws_size,
                              hipStream_t stream)
{
    (void)in_sizes; (void)n_in; (void)out_size; (void)ws_size;
    const float* hidden    = (const float*)d_in[0];
    const float* q_down_w  = (const float*)d_in[3];
    const float* kv_down_w = (const float*)d_in[4];
    const float* q_up_w    = (const float*)d_in[5];
    const float* k_up_w    = (const float*)d_in[6];
    const float* o_w       = (const float*)d_in[7];
    const float* q_norm_w  = (const float*)d_in[8];
    const float* kv_norm_w = (const float*)d_in[9];

    float* attnw = (float*)d_out;                        // 16*2048*2048 f32
    float* outp  = attnw + (size_t)NHEAD * SEQ * SEQ;    // 2048*2048 f32

    // ---- ws: buffers alive during/after the attention kernel (~47 MB) ----
    char* wp = (char*)d_ws;
    auto aws = [&](size_t bytes) { void* p = (void*)wp; wp += (bytes + 255) & ~(size_t)255; return p; };
    f16*  ow16  = (f16*)aws((size_t)2048 * 2048 * 2);
    f16*  Qf    = (f16*)aws((size_t)16 * 2048 * 192 * 2);
    f16*  Knope = (f16*)aws((size_t)16 * 2048 * 128 * 2);
    f16*  Vt    = (f16*)aws((size_t)16 * 128 * 2048 * 2);
    f16*  Krope = (f16*)aws((size_t)2048 * 64 * 2);
    f16*  Ohead = (f16*)aws((size_t)2048 * 2048 * 2);
    float* cs   = (float*)aws((size_t)2048 * 64 * 4);

    // ---- early-pipeline scratch lives inside d_out's attn region (overwritten later) ----
    char* sp = (char*)d_out;
    auto aso = [&](size_t bytes) { void* p = (void*)sp; sp += (bytes + 255) & ~(size_t)255; return p; };
    f16*  h16     = (f16*)aso((size_t)2048 * 2048 * 2);
    f16*  qdw16   = (f16*)aso((size_t)1536 * 2048 * 2);
    f16*  kvdw16  = (f16*)aso((size_t)640 * 2048 * 2);   // padded 576->640 rows
    f16*  quw16   = (f16*)aso((size_t)3072 * 1536 * 2);
    f16*  kuw16   = (f16*)aso((size_t)4096 * 512 * 2);
    float* cq_raw  = (float*)aso((size_t)2048 * 1536 * 4);
    float* ckv_raw = (float*)aso((size_t)2048 * 640 * 4);
    f16*  cq16     = (f16*)aso((size_t)2048 * 1536 * 2);
    f16*  latent16 = (f16*)aso((size_t)2048 * 512 * 2);
    float* q_all   = (float*)aso((size_t)2048 * 3072 * 4);
    float* kv_all  = (float*)aso((size_t)2048 * 4096 * 4);

    // 1. rope table
    k_rope_table<<<dim3(2048), dim3(32), 0, stream>>>(cs);

    // 2. f32 -> f16 conversions
    auto conv = [&](const float* s_, f16* d_, int nv, int nt) {
        k_cvt<<<dim3((nt + 1023) / 1024), dim3(256), 0, stream>>>(s_, d_, nv, nt);
    };
    conv(hidden,    h16,    2048 * 2048, 2048 * 2048);
    conv(q_down_w,  qdw16,  1536 * 2048, 1536 * 2048);
    conv(kv_down_w, kvdw16, 576 * 2048,  640 * 2048);
    conv(q_up_w,    quw16,  3072 * 1536, 3072 * 1536);
    conv(k_up_w,    kuw16,  4096 * 512,  4096 * 512);
    conv(o_w,       ow16,   2048 * 2048, 2048 * 2048);

    // 3-4. down-projections
    k_gemm<<<dim3(1536 / 128, 16), dim3(256), 0, stream>>>(h16, qdw16, cq_raw, 2048, 1536);
    k_gemm<<<dim3(640 / 128, 16),  dim3(256), 0, stream>>>(h16, kvdw16, ckv_raw, 2048, 640);

    // 5-6. RMS norms (+ k_pe rope)
    k_rms_q<<<dim3(2048),  dim3(256), 0, stream>>>(cq_raw, q_norm_w, cq16);
    k_rms_kv<<<dim3(2048), dim3(256), 0, stream>>>(ckv_raw, kv_norm_w, latent16, Krope, cs);

    // 7-8. up-projections
    k_gemm<<<dim3(3072 / 128, 16), dim3(256), 0, stream>>>(cq16, quw16, q_all, 1536, 3072);
    k_gemm<<<dim3(4096 / 128, 16), dim3(256), 0, stream>>>(latent16, kuw16, kv_all, 512, 4096);

    // 9-10. assemble Q (rope) / K_nope / V^T
    k_asm_q<<<dim3((16 * 2048 * 192) / 256), dim3(256), 0, stream>>>(q_all, cs, Qf);
    k_asm_kv<<<dim3((16 * 2048 * 256) / 256), dim3(256), 0, stream>>>(kv_all, Knope, Vt);

    // 11. fused attention: writes full attn_weights + Ohead
    k_attn<<<dim3(32, 16), dim3(256), 0, stream>>>(Qf, Krope, Knope, Vt, attnw, Ohead);

    // 12. output projection
    k_gemm<<<dim3(16, 16), dim3(256), 0, stream>>>(Ohead, ow16, outp, 2048, 2048);
}

// Round 2
// 514.594 us; speedup vs baseline: 1.6049x; 1.6049x over previous
//
#include <hip/hip_runtime.h>
#include <cstdint>
#include <cmath>

typedef _Float16 f16;
using f16x8 = __attribute__((ext_vector_type(8))) _Float16;
using f16x4 = __attribute__((ext_vector_type(4))) _Float16;
using f32x4 = __attribute__((ext_vector_type(4))) float;

#define NHEAD 16
#define SEQ   2048
#define NEG_INF -3.0e38f

static __device__ __forceinline__ f32x4 mfma16(f16x8 a, f16x8 b, f32x4 c) {
    return __builtin_amdgcn_mfma_f32_16x16x32_f16(a, b, c, 0, 0, 0);
}

// async global->LDS, 16B per lane: lds dest = wave-uniform base + lane*16
static __device__ __forceinline__ void gload16(const void* gp, void* lp) {
    __builtin_amdgcn_global_load_lds(
        (const __attribute__((address_space(1))) unsigned int*)gp,
        (__attribute__((address_space(3))) unsigned int*)lp, 16, 0, 0);
}

// ---------------- convert f32 -> f16 (with zero-padding tail) ----------------
__global__ __launch_bounds__(256) void k_cvt(const float* __restrict__ src, f16* __restrict__ dst,
                                             int n_valid, int n_total)
{
    int i = (blockIdx.x * 256 + threadIdx.x) * 4;
    if (i >= n_total) return;
    f16x4 o;
#pragma unroll
    for (int k = 0; k < 4; k++) {
        int idx = i + k;
        float v = (idx < n_valid) ? src[idx] : 0.f;
        o[k] = (f16)v;
    }
    *(f16x4*)&dst[i] = o;
}

// ---------------- RoPE cos/sin table ----------------
__global__ void k_rope_table(float* __restrict__ cs)
{
    int t = blockIdx.x;
    int j = threadIdx.x;            // 0..31
    float invf = (float)pow(10000.0, -(double)j / 32.0);
    float ang  = (float)t * invf;
    cs[t * 64 + j]      = (float)cos((double)ang);
    cs[t * 64 + 32 + j] = (float)sin((double)ang);
}

// ---------------- fp16 GEMM: C[M][ldc] = A[M][K] * B[N][K]^T (f32 out) ----------------
// 128x128 tile, BK=32, 4 waves, global_load_lds width-16 staging (m97 recipe)
__global__ __launch_bounds__(256) void k_gemm(const f16* __restrict__ A, const f16* __restrict__ B,
                                              float* __restrict__ C, int K, int ldc)
{
    __shared__ __align__(16) f16 As[128 * 32];
    __shared__ __align__(16) f16 Bs[128 * 32];
    const int tid  = threadIdx.x;
    const int lane = tid & 63;
    const int wv   = tid >> 6;
    const int l15  = lane & 15;
    const int lg   = lane >> 4;
    const int m0   = blockIdx.y * 128;
    const int n0   = blockIdx.x * 128;
    const int wm   = (wv >> 1) * 64;
    const int wn   = (wv & 1) * 64;

    f32x4 acc[4][4] = {};

    const int r0  = tid >> 2;          // 0..63
    const int kc0 = (tid & 3) * 8;     // 0,8,16,24

    // wave-uniform LDS bases: thread tid writes f16 offset tid*8 (= linear lane*16B)
    f16* asb0 = &As[(size_t)wv * 512];
    f16* asb1 = &As[2048 + (size_t)wv * 512];
    f16* bsb0 = &Bs[(size_t)wv * 512];
    f16* bsb1 = &Bs[2048 + (size_t)wv * 512];
    const f16* ap = &A[(size_t)(m0 + r0) * K + kc0];
    const f16* bp = &B[(size_t)(n0 + r0) * K + kc0];

    for (int kt = 0; kt < K; kt += 32) {
        __syncthreads();                       // prior reads done before overwrite
        gload16(ap + kt, asb0);
        gload16(ap + (size_t)64 * K + kt, asb1);
        gload16(bp + kt, bsb0);
        gload16(bp + (size_t)64 * K + kt, bsb1);
        __syncthreads();                       // drains vmcnt(0) + barrier
        f16x8 af[4], bf[4];
#pragma unroll
        for (int i = 0; i < 4; i++)
            af[i] = *(const f16x8*)&As[(wm + i * 16 + l15) * 32 + lg * 8];
#pragma unroll
        for (int i = 0; i < 4; i++)
            bf[i] = *(const f16x8*)&Bs[(wn + i * 16 + l15) * 32 + lg * 8];
#pragma unroll
        for (int i = 0; i < 4; i++)
#pragma unroll
            for (int j = 0; j < 4; j++)
                acc[i][j] = mfma16(af[i], bf[j], acc[i][j]);
    }
#pragma unroll
    for (int i = 0; i < 4; i++) {
#pragma unroll
        for (int j = 0; j < 4; j++) {
            const int row = m0 + wm + i * 16 + lg * 4;
            const int col = n0 + wn + j * 16 + l15;
#pragma unroll
            for (int r = 0; r < 4; r++)
                C[(size_t)(row + r) * ldc + col] = acc[i][j][r];
        }
    }
}

// ---------------- RMS norm (q path) ----------------
__global__ __launch_bounds__(256) void k_rms_q(const float* __restrict__ X, const float* __restrict__ w,
                                               f16* __restrict__ Y)
{
    const int row = blockIdx.x, tid = threadIdx.x;
    const float* x = &X[(size_t)row * 1536];
    float ss = 0.f;
    for (int c = tid; c < 1536; c += 256) { float v = x[c]; ss += v * v; }
#pragma unroll
    for (int off = 32; off > 0; off >>= 1) ss += __shfl_xor(ss, off);
    __shared__ float part[4];
    if ((tid & 63) == 0) part[tid >> 6] = ss;
    __syncthreads();
    float tot = part[0] + part[1] + part[2] + part[3];
    float sc = 1.f / sqrtf(tot / 1536.f + 1e-6f);
    for (int c = tid; c < 1536; c += 256)
        Y[(size_t)row * 1536 + c] = (f16)(w[c] * x[c] * sc);
}

// ---------------- RMS norm (kv path) + RoPE on k_pe ----------------
__global__ __launch_bounds__(256) void k_rms_kv(const float* __restrict__ X, const float* __restrict__ w,
                                                f16* __restrict__ Lat, f16* __restrict__ Krope,
                                                const float* __restrict__ cs)
{
    const int row = blockIdx.x, tid = threadIdx.x;
    const float* x = &X[(size_t)row * 640];
    float ss = 0.f;
    for (int c = tid; c < 576; c += 256) { float v = x[c]; ss += v * v; }
#pragma unroll
    for (int off = 32; off > 0; off >>= 1) ss += __shfl_xor(ss, off);
    __shared__ float part[4];
    if ((tid & 63) == 0) part[tid >> 6] = ss;
    __syncthreads();
    float tot = part[0] + part[1] + part[2] + part[3];
    float sc = 1.f / sqrtf(tot / 576.f + 1e-6f);
    for (int c = tid; c < 512; c += 256)
        Lat[(size_t)row * 512 + c] = (f16)(w[c] * x[c] * sc);
    if (tid < 32) {
        int j = tid;
        float a = w[512 + 2 * j] * x[512 + 2 * j] * sc;
        float b = w[512 + 2 * j + 1] * x[512 + 2 * j + 1] * sc;
        float cv = cs[row * 64 + j], sv = cs[row * 64 + 32 + j];
        Krope[row * 64 + j]      = (f16)(a * cv - b * sv);
        Krope[row * 64 + 32 + j] = (f16)(b * cv + a * sv);
    }
}

// ---------------- assemble Q ----------------
__global__ __launch_bounds__(256) void k_asm_q(const float* __restrict__ q_all, const float* __restrict__ cs,
                                               f16* __restrict__ Qf)
{
    size_t idx = (size_t)blockIdx.x * 256 + threadIdx.x;
    if (idx >= (size_t)16 * 2048 * 192) return;
    int d = (int)(idx % 192);
    size_t hs = idx / 192;
    int s = (int)(hs % 2048);
    int h = (int)(hs / 2048);
    const float* qrow = &q_all[(size_t)s * 3072 + h * 192];
    float v;
    if (d < 64) {
        int j = d & 31;
        float a = qrow[128 + 2 * j], b = qrow[128 + 2 * j + 1];
        float cv = cs[s * 64 + j], sv = cs[s * 64 + 32 + j];
        v = (d < 32) ? (a * cv - b * sv) : (b * cv + a * sv);
    } else {
        v = qrow[d - 64];
    }
    Qf[idx] = (f16)v;
}

// ---------------- assemble K_nope + V^T ----------------
__global__ __launch_bounds__(256) void k_asm_kv(const float* __restrict__ kv_all,
                                                f16* __restrict__ Knope,  // [16][2048][128]
                                                f16* __restrict__ Vt)     // [16][128][2048]
{
    size_t idx = (size_t)blockIdx.x * 256 + threadIdx.x;
    if (idx >= (size_t)16 * 2048 * 256) return;
    int d = (int)(idx % 256);
    size_t hs = idx / 256;
    int s = (int)(hs % 2048);
    int h = (int)(hs / 2048);
    float v = kv_all[(size_t)s * 4096 + h * 256 + d];
    if (d < 128)
        Knope[((size_t)h * 2048 + s) * 128 + d] = (f16)v;
    else
        Vt[((size_t)h * 128 + (d - 128)) * 2048 + s] = (f16)v;
}

// ---------------- stage A: one-pass flash attention, writes raw S + m/rl + Ohead ----------------
// grid (32,16); qtile swizzled for load balance; 4 waves, wave owns 16 q-rows.
__global__ __launch_bounds__(256) void k_attn2(
    const f16* __restrict__ Qf,     // [16][2048][192]
    const f16* __restrict__ Krope,  // [2048][64]
    const f16* __restrict__ Knope,  // [16][2048][128]
    const f16* __restrict__ Vt,     // [16][128][2048]
    float* __restrict__ attnw,      // [16][2048][2048] raw S (lower tri)
    float* __restrict__ mlbuf,      // [16][2048][2]  (m, 1/l)
    f16* __restrict__ Ohead)        // [2048][16*128]
{
    const int h  = blockIdx.y;
    const int qt = (h >= 8) ? (31 - (int)blockIdx.x) : (int)blockIdx.x; // balance pairing
    const int q0 = qt * 64;
    const int tid = threadIdx.x;
    const int lane = tid & 63;
    const int wv = tid >> 6;
    const int l15 = lane & 15;
    const int lg  = lane >> 4;
    const int rowb = q0 + wv * 16;

    __shared__ __align__(16) f16 Ks[64][200];     // rope(64)|nope(128), pad->200 (2-way banks)
    __shared__ __align__(16) f16 Vs[128][72];     // [d][kv], pad->72
    __shared__ __align__(16) f16 Plds[4][16][72];

    f16x8 qf[6];
    {
        const f16* qbase = &Qf[((size_t)h * SEQ + rowb + l15) * 192];
#pragma unroll
        for (int kf = 0; kf < 6; kf++)
            qf[kf] = *(const f16x8*)&qbase[kf * 32 + lg * 8];
    }

    float m[4], l[4];
#pragma unroll
    for (int r = 0; r < 4; r++) { m[r] = NEG_INF; l[r] = 0.f; }
    f32x4 o[8] = {};

    const int ntiles = qt + 1;
    const f32x4 vzero = {0.f, 0.f, 0.f, 0.f};
    const int srow = tid >> 2;      // staging row 0..63
    const int sp4  = tid & 3;

    for (int t = 0; t < ntiles; t++) {
        const int c0 = t * 64;
        __syncthreads();            // protect Ks/Vs from overwrite while in use
        // ---- stage K tile: 64 rows x 192 dims ----
#pragma unroll
        for (int i = 0; i < 6; i++) {
            const int p = sp4 + 4 * i;
            f16x8 v;
            if (p < 8) v = *(const f16x8*)&Krope[(size_t)(c0 + srow) * 64 + p * 8];
            else       v = *(const f16x8*)&Knope[((size_t)h * SEQ + c0 + srow) * 128 + (p - 8) * 8];
            *(f16x8*)&Ks[srow][p * 8] = v;
        }
        // ---- stage V tile: 128 d x 64 kv ----
#pragma unroll
        for (int i = 0; i < 4; i++) {
            const int c = tid + 256 * i;
            const int d = c >> 3, x = c & 7;
            *(f16x8*)&Vs[d][x * 8] = *(const f16x8*)&Vt[((size_t)h * 128 + d) * SEQ + c0 + x * 8];
        }
        __syncthreads();

        // ---- S = Q K^T (from LDS) ----
        f32x4 s[4];
#pragma unroll
        for (int ni = 0; ni < 4; ni++) {
            s[ni] = vzero;
            const f16* kp = &Ks[ni * 16 + l15][0];
#pragma unroll
            for (int kf = 0; kf < 6; kf++)
                s[ni] = mfma16(qf[kf], *(const f16x8*)&kp[kf * 32 + lg * 8], s[ni]);
        }

        // ---- store raw S, mask, row max ----
        float vmax[4] = {NEG_INF, NEG_INF, NEG_INF, NEG_INF};
#pragma unroll
        for (int ni = 0; ni < 4; ni++) {
            const int col = c0 + ni * 16 + l15;
#pragma unroll
            for (int r = 0; r < 4; r++) {
                const int row = rowb + lg * 4 + r;
                attnw[((size_t)h * SEQ + row) * SEQ + col] = s[ni][r];
                float v = (col <= row) ? s[ni][r] : NEG_INF;
                s[ni][r] = v;
                vmax[r] = fmaxf(vmax[r], v);
            }
        }
#pragma unroll
        for (int off = 1; off < 16; off <<= 1)
#pragma unroll
            for (int r = 0; r < 4; r++)
                vmax[r] = fmaxf(vmax[r], __shfl_xor(vmax[r], off));

        float fscale[4];
#pragma unroll
        for (int r = 0; r < 4; r++) {
            const float nm = fmaxf(m[r], vmax[r]);
            fscale[r] = expf(m[r] - nm);
            float es = 0.f;
#pragma unroll
            for (int ni = 0; ni < 4; ni++) {
                float p = expf(s[ni][r] - nm);
                s[ni][r] = p;
                es += p;
            }
#pragma unroll
            for (int off = 1; off < 16; off <<= 1) es += __shfl_xor(es, off);
            l[r] = l[r] * fscale[r] + es;
            m[r] = nm;
        }
        // rescale O, write P to LDS
#pragma unroll
        for (int nd = 0; nd < 8; nd++)
#pragma unroll
            for (int r = 0; r < 4; r++) o[nd][r] *= fscale[r];
#pragma unroll
        for (int ni = 0; ni < 4; ni++)
#pragma unroll
            for (int r = 0; r < 4; r++)
                Plds[wv][lg * 4 + r][ni * 16 + l15] = (f16)s[ni][r];
        asm volatile("" ::: "memory");

        // ---- O += P * V ----
        f16x8 pa0 = *(const f16x8*)&Plds[wv][l15][lg * 8];
        f16x8 pa1 = *(const f16x8*)&Plds[wv][l15][32 + lg * 8];
#pragma unroll
        for (int nd = 0; nd < 8; nd++) {
            const f16* vp = &Vs[nd * 16 + l15][lg * 8];
            o[nd] = mfma16(pa0, *(const f16x8*)&vp[0],  o[nd]);
            o[nd] = mfma16(pa1, *(const f16x8*)&vp[32], o[nd]);
        }
    }

    float rl[4];
#pragma unroll
    for (int r = 0; r < 4; r++) rl[r] = 1.f / l[r];

#pragma unroll
    for (int nd = 0; nd < 8; nd++)
#pragma unroll
        for (int r = 0; r < 4; r++) {
            const int row = rowb + lg * 4 + r;
            Ohead[(size_t)row * 2048 + h * 128 + nd * 16 + l15] = (f16)(o[nd][r] * rl[r]);
        }
    if (l15 == 0) {
#pragma unroll
        for (int r = 0; r < 4; r++) {
            const int row = rowb + lg * 4 + r;
            mlbuf[((size_t)h * SEQ + row) * 2]     = m[r];
            mlbuf[((size_t)h * SEQ + row) * 2 + 1] = rl[r];
        }
    }
}

// ---------------- stage B: normalize S -> P in place (streaming, balanced) ----------------
__global__ __launch_bounds__(256) void k_norm(float* __restrict__ attnw, const float* __restrict__ ml)
{
    const int h  = blockIdx.y;
    const int r0 = blockIdx.x * 32;
    const int tid = threadIdx.x;
    for (int it = 0; it < 64; it++) {
        const int row = r0 + (it >> 1);
        const int cq  = ((it & 1) * 256 + tid) * 4;
        float* p = &attnw[((size_t)h * SEQ + row) * SEQ + cq];
        const float mr = ml[((size_t)h * SEQ + row) * 2];
        const float rl = ml[((size_t)h * SEQ + row) * 2 + 1];
        if (cq <= row) {
            f32x4 v = *(const f32x4*)p;
            f32x4 ov;
#pragma unroll
            for (int k = 0; k < 4; k++)
                ov[k] = (cq + k <= row) ? expf(v[k] - mr) * rl : 0.f;
            *(f32x4*)p = ov;
        } else {
            *(f32x4*)p = f32x4{0.f, 0.f, 0.f, 0.f};
        }
    }
}

extern "C" void kernel_launch(void* const* d_in, const int* in_sizes, int n_in,
                              void* d_out, int out_size, void* d_ws, size_t ws_size,
                              hipStream_t stream)
{
    (void)in_sizes; (void)n_in; (void)out_size; (void)ws_size;
    const float* hidden    = (const float*)d_in[0];
    const float* q_down_w  = (const float*)d_in[3];
    const float* kv_down_w = (const float*)d_in[4];
    const float* q_up_w    = (const float*)d_in[5];
    const float* k_up_w    = (const float*)d_in[6];
    const float* o_w       = (const float*)d_in[7];
    const float* q_norm_w  = (const float*)d_in[8];
    const float* kv_norm_w = (const float*)d_in[9];

    float* attnw = (float*)d_out;                        // 16*2048*2048 f32
    float* outp  = attnw + (size_t)NHEAD * SEQ * SEQ;    // 2048*2048 f32

    // ---- ws: buffers alive during/after the attention kernel ----
    char* wp = (char*)d_ws;
    auto aws = [&](size_t bytes) { void* p = (void*)wp; wp += (bytes + 255) & ~(size_t)255; return p; };
    f16*  ow16  = (f16*)aws((size_t)2048 * 2048 * 2);
    f16*  Qf    = (f16*)aws((size_t)16 * 2048 * 192 * 2);
    f16*  Knope = (f16*)aws((size_t)16 * 2048 * 128 * 2);
    f16*  Vt    = (f16*)aws((size_t)16 * 128 * 2048 * 2);
    f16*  Krope = (f16*)aws((size_t)2048 * 64 * 2);
    f16*  Ohead = (f16*)aws((size_t)2048 * 2048 * 2);
    float* cs   = (float*)aws((size_t)2048 * 64 * 4);
    float* mlbuf= (float*)aws((size_t)16 * 2048 * 2 * 4);

    // ---- early-pipeline scratch inside d_out's attn region (overwritten later) ----
    char* sp = (char*)d_out;
    auto aso = [&](size_t bytes) { void* p = (void*)sp; sp += (bytes + 255) & ~(size_t)255; return p; };
    f16*  h16     = (f16*)aso((size_t)2048 * 2048 * 2);
    f16*  qdw16   = (f16*)aso((size_t)1536 * 2048 * 2);
    f16*  kvdw16  = (f16*)aso((size_t)640 * 2048 * 2);
    f16*  quw16   = (f16*)aso((size_t)3072 * 1536 * 2);
    f16*  kuw16   = (f16*)aso((size_t)4096 * 512 * 2);
    float* cq_raw  = (float*)aso((size_t)2048 * 1536 * 4);
    float* ckv_raw = (float*)aso((size_t)2048 * 640 * 4);
    f16*  cq16     = (f16*)aso((size_t)2048 * 1536 * 2);
    f16*  latent16 = (f16*)aso((size_t)2048 * 512 * 2);
    float* q_all   = (float*)aso((size_t)2048 * 3072 * 4);
    float* kv_all  = (float*)aso((size_t)2048 * 4096 * 4);

    k_rope_table<<<dim3(2048), dim3(32), 0, stream>>>(cs);

    auto conv = [&](const float* s_, f16* d_, int nv, int nt) {
        k_cvt<<<dim3((nt + 1023) / 1024), dim3(256), 0, stream>>>(s_, d_, nv, nt);
    };
    conv(hidden,    h16,    2048 * 2048, 2048 * 2048);
    conv(q_down_w,  qdw16,  1536 * 2048, 1536 * 2048);
    conv(kv_down_w, kvdw16, 576 * 2048,  640 * 2048);
    conv(q_up_w,    quw16,  3072 * 1536, 3072 * 1536);
    conv(k_up_w,    kuw16,  4096 * 512,  4096 * 512);
    conv(o_w,       ow16,   2048 * 2048, 2048 * 2048);

    k_gemm<<<dim3(1536 / 128, 16), dim3(256), 0, stream>>>(h16, qdw16, cq_raw, 2048, 1536);
    k_gemm<<<dim3(640 / 128, 16),  dim3(256), 0, stream>>>(h16, kvdw16, ckv_raw, 2048, 640);

    k_rms_q<<<dim3(2048),  dim3(256), 0, stream>>>(cq_raw, q_norm_w, cq16);
    k_rms_kv<<<dim3(2048), dim3(256), 0, stream>>>(ckv_raw, kv_norm_w, latent16, Krope, cs);

    k_gemm<<<dim3(3072 / 128, 16), dim3(256), 0, stream>>>(cq16, quw16, q_all, 1536, 3072);
    k_gemm<<<dim3(4096 / 128, 16), dim3(256), 0, stream>>>(latent16, kuw16, kv_all, 512, 4096);

    k_asm_q<<<dim3((16 * 2048 * 192) / 256), dim3(256), 0, stream>>>(q_all, cs, Qf);
    k_asm_kv<<<dim3((16 * 2048 * 256) / 256), dim3(256), 0, stream>>>(kv_all, Knope, Vt);

    // stage A: flash attention, raw S + m/rl + Ohead
    k_attn2<<<dim3(32, 16), dim3(256), 0, stream>>>(Qf, Krope, Knope, Vt, attnw, mlbuf, Ohead);
    // stage B: normalize to P (writes every element incl. zeros)
    k_norm<<<dim3(64, 16), dim3(256), 0, stream>>>(attnw, mlbuf);

    // output projection
    k_gemm<<<dim3(16, 16), dim3(256), 0, stream>>>(Ohead, ow16, outp, 2048, 2048);
}